// Round 1
// baseline (10060.278 us; speedup 1.0000x reference)
//
#include <hip/hip_runtime.h>
#include <math.h>

// GCN: h1 = relu(norm_agg(x@W1) + b1); h2 = relu(norm_agg(h1@W2) + b2);
// out = sigmoid(h2@fc_w + fc_b)
// norm_agg(z)[d] = dinv[d]*( sum_{s->d} dinv[s]*z[s] + dinv[d]*z[d] )

static inline int idiv_up(long a, long b) { return (int)((a + b - 1) / b); }

__global__ void k_deg(const int* __restrict__ dst, long E, unsigned* __restrict__ deg) {
    long i = (long)blockIdx.x * blockDim.x + threadIdx.x;
    long stride = (long)gridDim.x * blockDim.x;
    for (long e = i; e < E; e += stride)
        atomicAdd(&deg[dst[e]], 1u);
}

__global__ void k_dinv(const unsigned* __restrict__ deg, float* __restrict__ dinv, int N) {
    int i = blockIdx.x * blockDim.x + threadIdx.x;
    if (i < N) dinv[i] = rsqrtf((float)(deg[i] + 1u));  // +1 self-loop
}

// y1[i] = (x[i] @ W1) * dinv[i]; acc1[i] = y1[i]  (self-loop init)
__global__ void k_node1(const float* __restrict__ x, const float* __restrict__ W1,
                        const float* __restrict__ dinv, float* __restrict__ y1,
                        float* __restrict__ acc1, int N) {
    __shared__ float sW[192];  // W1 is [12][16] row-major
    if (threadIdx.x < 192) sW[threadIdx.x] = W1[threadIdx.x];
    __syncthreads();
    int i = blockIdx.x * blockDim.x + threadIdx.x;
    if (i >= N) return;
    const float4* xp = (const float4*)(x + (size_t)i * 12);  // 48B rows, 16B aligned
    float4 a = xp[0], b = xp[1], c = xp[2];
    float xi[12] = {a.x, a.y, a.z, a.w, b.x, b.y, b.z, b.w, c.x, c.y, c.z, c.w};
    float di = dinv[i];
    float o[16];
#pragma unroll
    for (int cc = 0; cc < 16; ++cc) {
        float s = 0.f;
#pragma unroll
        for (int r = 0; r < 12; ++r) s = fmaf(xi[r], sW[r * 16 + cc], s);
        o[cc] = s * di;
    }
    float4* yp = (float4*)(y1 + (size_t)i * 16);
    float4* ap = (float4*)(acc1 + (size_t)i * 16);
#pragma unroll
    for (int q = 0; q < 4; ++q) {
        float4 v = make_float4(o[4 * q], o[4 * q + 1], o[4 * q + 2], o[4 * q + 3]);
        yp[q] = v;
        ap[q] = v;
    }
}

// scatter: acc[dst] += y[src], C floats per node
template <int C>
__global__ void k_edge(const int* __restrict__ src, const int* __restrict__ dst, long E,
                       const float* __restrict__ y, float* __restrict__ acc) {
    long i = (long)blockIdx.x * blockDim.x + threadIdx.x;
    long stride = (long)gridDim.x * blockDim.x;
    for (long e = i; e < E; e += stride) {
        int s = src[e], d = dst[e];
        const float4* ys = (const float4*)(y + (size_t)s * C);
        float* ad = acc + (size_t)d * C;
#pragma unroll
        for (int q = 0; q < C / 4; ++q) {
            float4 v = ys[q];
            unsafeAtomicAdd(ad + 4 * q + 0, v.x);  // native global_atomic_add_f32
            unsafeAtomicAdd(ad + 4 * q + 1, v.y);
            unsafeAtomicAdd(ad + 4 * q + 2, v.z);
            unsafeAtomicAdd(ad + 4 * q + 3, v.w);
        }
    }
}

// h1 = relu(acc1*dinv + b1); y2 = (h1 @ W2)*dinv; acc2 = y2
__global__ void k_node2(const float* __restrict__ acc1, const float* __restrict__ W2,
                        const float* __restrict__ b1, const float* __restrict__ dinv,
                        float* __restrict__ y2, float* __restrict__ acc2, int N) {
    __shared__ float sW[128];  // W2 [16][8] row-major
    __shared__ float sb[16];
    if (threadIdx.x < 128) sW[threadIdx.x] = W2[threadIdx.x];
    if (threadIdx.x < 16) sb[threadIdx.x] = b1[threadIdx.x];
    __syncthreads();
    int i = blockIdx.x * blockDim.x + threadIdx.x;
    if (i >= N) return;
    float di = dinv[i];
    const float4* ap = (const float4*)(acc1 + (size_t)i * 16);
    float h[16];
#pragma unroll
    for (int q = 0; q < 4; ++q) {
        float4 v = ap[q];
        h[4 * q + 0] = fmaxf(fmaf(v.x, di, sb[4 * q + 0]), 0.f);
        h[4 * q + 1] = fmaxf(fmaf(v.y, di, sb[4 * q + 1]), 0.f);
        h[4 * q + 2] = fmaxf(fmaf(v.z, di, sb[4 * q + 2]), 0.f);
        h[4 * q + 3] = fmaxf(fmaf(v.w, di, sb[4 * q + 3]), 0.f);
    }
    float o[8];
#pragma unroll
    for (int k = 0; k < 8; ++k) {
        float s = 0.f;
#pragma unroll
        for (int c = 0; c < 16; ++c) s = fmaf(h[c], sW[c * 8 + k], s);
        o[k] = s * di;
    }
    float4* yp = (float4*)(y2 + (size_t)i * 8);
    float4* a2 = (float4*)(acc2 + (size_t)i * 8);
#pragma unroll
    for (int q = 0; q < 2; ++q) {
        float4 v = make_float4(o[4 * q], o[4 * q + 1], o[4 * q + 2], o[4 * q + 3]);
        yp[q] = v;
        a2[q] = v;
    }
}

// h2 = relu(acc2*dinv + b2); out = sigmoid(h2 @ fc_w + fc_b)
__global__ void k_node3(const float* __restrict__ acc2, const float* __restrict__ b2,
                        const float* __restrict__ fcw, const float* __restrict__ fcb,
                        const float* __restrict__ dinv, float* __restrict__ out, int N) {
    __shared__ float sb[8], sw[8], sfb[1];
    if (threadIdx.x < 8) {
        sb[threadIdx.x] = b2[threadIdx.x];
        sw[threadIdx.x] = fcw[threadIdx.x];
    }
    if (threadIdx.x == 0) sfb[0] = fcb[0];
    __syncthreads();
    int i = blockIdx.x * blockDim.x + threadIdx.x;
    if (i >= N) return;
    float di = dinv[i];
    const float4* ap = (const float4*)(acc2 + (size_t)i * 8);
    float s = sfb[0];
#pragma unroll
    for (int q = 0; q < 2; ++q) {
        float4 v = ap[q];
        s = fmaf(fmaxf(fmaf(v.x, di, sb[4 * q + 0]), 0.f), sw[4 * q + 0], s);
        s = fmaf(fmaxf(fmaf(v.y, di, sb[4 * q + 1]), 0.f), sw[4 * q + 1], s);
        s = fmaf(fmaxf(fmaf(v.z, di, sb[4 * q + 2]), 0.f), sw[4 * q + 2], s);
        s = fmaf(fmaxf(fmaf(v.w, di, sb[4 * q + 3]), 0.f), sw[4 * q + 3], s);
    }
    out[i] = 1.f / (1.f + expf(-s));
}

extern "C" void kernel_launch(void* const* d_in, const int* in_sizes, int n_in,
                              void* d_out, int out_size, void* d_ws, size_t ws_size,
                              hipStream_t stream) {
    const float* x   = (const float*)d_in[0];
    const int*   ei  = (const int*)d_in[1];
    const float* W1  = (const float*)d_in[2];
    const float* b1  = (const float*)d_in[3];
    const float* W2  = (const float*)d_in[4];
    const float* b2  = (const float*)d_in[5];
    const float* fcw = (const float*)d_in[6];
    const float* fcb = (const float*)d_in[7];
    float* out = (float*)d_out;

    const long N = in_sizes[0] / 12;
    const long E = in_sizes[1] / 2;
    const int* src = ei;       // edge_index[0]
    const int* dst = ei + E;   // edge_index[1]

    // workspace layout (all 256B-aligned); y2/acc2 alias y1's region (dead after edge1)
    char* ws = (char*)d_ws;
    size_t off = 0;
    auto alloc = [&](size_t bytes) {
        void* p = ws + off;
        off += (bytes + 255) & ~(size_t)255;
        return p;
    };
    unsigned* deg  = (unsigned*)alloc((size_t)N * 4);
    float*    dinv = (float*)alloc((size_t)N * 4);
    float*    y1   = (float*)alloc((size_t)N * 16 * 4);
    float*    acc1 = (float*)alloc((size_t)N * 16 * 4);
    float*    y2   = y1;            // reuse: y1 dead after edge1
    float*    acc2 = y1 + N * 8;    // second half of y1 region

    const int B = 256;
    const int EG = 2048;  // grid-stride blocks for edge kernels
    const int NG = idiv_up(N, B);

    hipMemsetAsync(deg, 0, (size_t)N * 4, stream);
    k_deg<<<EG, B, 0, stream>>>(dst, E, deg);
    k_dinv<<<NG, B, 0, stream>>>(deg, dinv, (int)N);
    k_node1<<<NG, B, 0, stream>>>(x, W1, dinv, y1, acc1, (int)N);
    k_edge<16><<<EG, B, 0, stream>>>(src, dst, E, y1, acc1);
    k_node2<<<NG, B, 0, stream>>>(acc1, W2, b1, dinv, y2, acc2, (int)N);
    k_edge<8><<<EG, B, 0, stream>>>(src, dst, E, y2, acc2);
    k_node3<<<NG, B, 0, stream>>>(acc2, b2, fcw, fcb, dinv, out, (int)N);
}

// Round 2
// 1396.128 us; speedup vs baseline: 7.2058x; 7.2058x over previous
//
#include <hip/hip_runtime.h>
#include <math.h>

// GCN: h1 = relu(norm_agg(x@W1) + b1); h2 = relu(norm_agg(h1@W2) + b2);
// out = sigmoid(h2@fc_w + fc_b)
// norm_agg(z)[d] = dinv[d]*( sum_{s->d} dinv[s]*z[s] + dinv[d]*z[d] )
// Strategy: y[i] = (z[i]@W)*dinv[i]; acc[d] = sum_{s->d} y[s] + y[d];
//           finalize: relu(acc*dinv + b).
// Round 2: replace f32 atomic scatter (32B HBM write-through per atomic, 4GB+2GB)
// with CSR build (counting sort by dst) + deterministic gather.

static inline int idiv_up(long a, long b) { return (int)((a + b - 1) / b); }

// ---------------- degree / norm ----------------
__global__ void k_deg(const int* __restrict__ dst, long E, unsigned* __restrict__ deg) {
    long i = (long)blockIdx.x * blockDim.x + threadIdx.x;
    long stride = (long)gridDim.x * blockDim.x;
    for (long e = i; e < E; e += stride)
        atomicAdd(&deg[dst[e]], 1u);  // 2MB array: absorbed by per-XCD L2 (cheap)
}

__global__ void k_dinv(const unsigned* __restrict__ deg, float* __restrict__ dinv, int N) {
    int i = blockIdx.x * blockDim.x + threadIdx.x;
    if (i < N) dinv[i] = rsqrtf((float)(deg[i] + 1u));  // +1 self-loop
}

// ---------------- CSR build: scan + scatter ----------------
// 1024 elems per block (256 thr x 4)
__global__ void k_bsum(const unsigned* __restrict__ deg, int N, unsigned* __restrict__ bsum) {
    __shared__ unsigned s[256];
    int base = blockIdx.x * 1024 + threadIdx.x * 4;
    unsigned t = 0;
#pragma unroll
    for (int j = 0; j < 4; ++j) { int idx = base + j; if (idx < N) t += deg[idx]; }
    s[threadIdx.x] = t;
    __syncthreads();
    for (int o = 128; o > 0; o >>= 1) {
        if (threadIdx.x < (unsigned)o) s[threadIdx.x] += s[threadIdx.x + o];
        __syncthreads();
    }
    if (threadIdx.x == 0) bsum[blockIdx.x] = s[0];
}

// single block, 512 threads: in-place exclusive scan of bsum[NB] with carry chunks
__global__ void k_scan_boff(unsigned* bsum, int NB) {
    __shared__ unsigned s[512];
    unsigned carry = 0;
    for (int base = 0; base < NB; base += 512) {
        int idx = base + threadIdx.x;
        unsigned v = (idx < NB) ? bsum[idx] : 0u;
        s[threadIdx.x] = v;
        __syncthreads();
        for (int o = 1; o < 512; o <<= 1) {
            unsigned a = (threadIdx.x >= (unsigned)o) ? s[threadIdx.x - o] : 0u;
            __syncthreads();
            s[threadIdx.x] += a;
            __syncthreads();
        }
        if (idx < NB) bsum[idx] = carry + s[threadIdx.x] - v;  // exclusive
        unsigned tot = s[511];
        __syncthreads();
        carry += tot;
    }
}

__global__ void k_scan_final(const unsigned* __restrict__ deg, int N,
                             const unsigned* __restrict__ boff,
                             unsigned* __restrict__ row_start, unsigned* __restrict__ cursor) {
    __shared__ unsigned s[256];
    int base = blockIdx.x * 1024 + threadIdx.x * 4;
    unsigned v[4]; unsigned t = 0;
#pragma unroll
    for (int j = 0; j < 4; ++j) { int idx = base + j; v[j] = (idx < N) ? deg[idx] : 0u; t += v[j]; }
    s[threadIdx.x] = t;
    __syncthreads();
    for (int o = 1; o < 256; o <<= 1) {  // inclusive Hillis-Steele
        unsigned a = (threadIdx.x >= (unsigned)o) ? s[threadIdx.x - o] : 0u;
        __syncthreads();
        s[threadIdx.x] += a;
        __syncthreads();
    }
    unsigned run = s[threadIdx.x] - t + boff[blockIdx.x];  // exclusive + block offset
#pragma unroll
    for (int j = 0; j < 4; ++j) {
        int idx = base + j;
        if (idx < N) { row_start[idx] = run; cursor[idx] = run; run += v[j]; }
    }
}

__global__ void k_scatter(const int* __restrict__ src, const int* __restrict__ dst, long E,
                          unsigned* __restrict__ cursor, int* __restrict__ csr) {
    long i = (long)blockIdx.x * blockDim.x + threadIdx.x;
    long stride = (long)gridDim.x * blockDim.x;
    for (long e = i; e < E; e += stride) {
        int d = dst[e];
        unsigned pos = atomicAdd(&cursor[d], 1u);  // int atomics on 2MB: L2-absorbed
        csr[pos] = src[e];
    }
}

// ---------------- gather: acc[d] = sum_{s in N(d)} y[s] + y[d] ----------------
// C lanes per node, one channel per lane; after k_scatter cursor[d] == row_end[d]
template <int C>
__global__ void k_gather(const unsigned* __restrict__ row_start, const unsigned* __restrict__ row_end,
                         const int* __restrict__ csr, const float* __restrict__ y,
                         float* __restrict__ acc, int N) {
    const int NPB = 256 / C;
    int g = threadIdx.x / C, c = threadIdx.x % C;
    int d = blockIdx.x * NPB + g;
    if (d >= N) return;
    unsigned b = row_start[d], en = row_end[d];
    float val = y[(size_t)d * C + c];  // self-loop term
    for (unsigned k = b; k < en; ++k) {
        int s = csr[k];
        val += y[(size_t)s * C + c];  // 64B/32B contiguous per lane-group, L2/L3-resident
    }
    acc[(size_t)d * C + c] = val;
}

// ---------------- fallback: f32 atomic scatter (round-1 path) ----------------
template <int C>
__global__ void k_edge(const int* __restrict__ src, const int* __restrict__ dst, long E,
                       const float* __restrict__ y, float* __restrict__ acc) {
    long i = (long)blockIdx.x * blockDim.x + threadIdx.x;
    long stride = (long)gridDim.x * blockDim.x;
    for (long e = i; e < E; e += stride) {
        int s = src[e], d = dst[e];
        const float4* ys = (const float4*)(y + (size_t)s * C);
        float* ad = acc + (size_t)d * C;
#pragma unroll
        for (int q = 0; q < C / 4; ++q) {
            float4 v = ys[q];
            unsafeAtomicAdd(ad + 4 * q + 0, v.x);
            unsafeAtomicAdd(ad + 4 * q + 1, v.y);
            unsafeAtomicAdd(ad + 4 * q + 2, v.z);
            unsafeAtomicAdd(ad + 4 * q + 3, v.w);
        }
    }
}

// ---------------- node kernels ----------------
// y1[i] = (x[i]@W1)*dinv[i]; acc1[i] = y1[i] (self-loop init, used by fallback path)
__global__ void k_node1(const float* __restrict__ x, const float* __restrict__ W1,
                        const float* __restrict__ dinv, float* __restrict__ y1,
                        float* __restrict__ acc1, int N) {
    __shared__ float sW[192];  // W1 [12][16]
    if (threadIdx.x < 192) sW[threadIdx.x] = W1[threadIdx.x];
    __syncthreads();
    int i = blockIdx.x * blockDim.x + threadIdx.x;
    if (i >= N) return;
    const float4* xp = (const float4*)(x + (size_t)i * 12);
    float4 a = xp[0], b = xp[1], c = xp[2];
    float xi[12] = {a.x, a.y, a.z, a.w, b.x, b.y, b.z, b.w, c.x, c.y, c.z, c.w};
    float di = dinv[i];
    float o[16];
#pragma unroll
    for (int cc = 0; cc < 16; ++cc) {
        float s = 0.f;
#pragma unroll
        for (int r = 0; r < 12; ++r) s = fmaf(xi[r], sW[r * 16 + cc], s);
        o[cc] = s * di;
    }
    float4* yp = (float4*)(y1 + (size_t)i * 16);
    float4* ap = (float4*)(acc1 + (size_t)i * 16);
#pragma unroll
    for (int q = 0; q < 4; ++q) {
        float4 v = make_float4(o[4 * q], o[4 * q + 1], o[4 * q + 2], o[4 * q + 3]);
        yp[q] = v;
        ap[q] = v;
    }
}

// h1 = relu(acc1*dinv + b1); y2 = (h1@W2)*dinv; acc2 = y2
__global__ void k_node2(const float* __restrict__ acc1, const float* __restrict__ W2,
                        const float* __restrict__ b1, const float* __restrict__ dinv,
                        float* __restrict__ y2, float* __restrict__ acc2, int N) {
    __shared__ float sW[128];  // W2 [16][8]
    __shared__ float sb[16];
    if (threadIdx.x < 128) sW[threadIdx.x] = W2[threadIdx.x];
    if (threadIdx.x < 16) sb[threadIdx.x] = b1[threadIdx.x];
    __syncthreads();
    int i = blockIdx.x * blockDim.x + threadIdx.x;
    if (i >= N) return;
    float di = dinv[i];
    const float4* ap = (const float4*)(acc1 + (size_t)i * 16);
    float h[16];
#pragma unroll
    for (int q = 0; q < 4; ++q) {
        float4 v = ap[q];
        h[4 * q + 0] = fmaxf(fmaf(v.x, di, sb[4 * q + 0]), 0.f);
        h[4 * q + 1] = fmaxf(fmaf(v.y, di, sb[4 * q + 1]), 0.f);
        h[4 * q + 2] = fmaxf(fmaf(v.z, di, sb[4 * q + 2]), 0.f);
        h[4 * q + 3] = fmaxf(fmaf(v.w, di, sb[4 * q + 3]), 0.f);
    }
    float o[8];
#pragma unroll
    for (int k = 0; k < 8; ++k) {
        float s = 0.f;
#pragma unroll
        for (int c = 0; c < 16; ++c) s = fmaf(h[c], sW[c * 8 + k], s);
        o[k] = s * di;
    }
    float4* yp = (float4*)(y2 + (size_t)i * 8);
    float4* a2 = (float4*)(acc2 + (size_t)i * 8);
#pragma unroll
    for (int q = 0; q < 2; ++q) {
        float4 v = make_float4(o[4 * q], o[4 * q + 1], o[4 * q + 2], o[4 * q + 3]);
        yp[q] = v;
        a2[q] = v;
    }
}

// h2 = relu(acc2*dinv + b2); out = sigmoid(h2@fc_w + fc_b)
__global__ void k_node3(const float* __restrict__ acc2, const float* __restrict__ b2,
                        const float* __restrict__ fcw, const float* __restrict__ fcb,
                        const float* __restrict__ dinv, float* __restrict__ out, int N) {
    __shared__ float sb[8], sw[8], sfb[1];
    if (threadIdx.x < 8) {
        sb[threadIdx.x] = b2[threadIdx.x];
        sw[threadIdx.x] = fcw[threadIdx.x];
    }
    if (threadIdx.x == 0) sfb[0] = fcb[0];
    __syncthreads();
    int i = blockIdx.x * blockDim.x + threadIdx.x;
    if (i >= N) return;
    float di = dinv[i];
    const float4* ap = (const float4*)(acc2 + (size_t)i * 8);
    float s = sfb[0];
#pragma unroll
    for (int q = 0; q < 2; ++q) {
        float4 v = ap[q];
        s = fmaf(fmaxf(fmaf(v.x, di, sb[4 * q + 0]), 0.f), sw[4 * q + 0], s);
        s = fmaf(fmaxf(fmaf(v.y, di, sb[4 * q + 1]), 0.f), sw[4 * q + 1], s);
        s = fmaf(fmaxf(fmaf(v.z, di, sb[4 * q + 2]), 0.f), sw[4 * q + 2], s);
        s = fmaf(fmaxf(fmaf(v.w, di, sb[4 * q + 3]), 0.f), sw[4 * q + 3], s);
    }
    out[i] = 1.f / (1.f + expf(-s));
}

extern "C" void kernel_launch(void* const* d_in, const int* in_sizes, int n_in,
                              void* d_out, int out_size, void* d_ws, size_t ws_size,
                              hipStream_t stream) {
    const float* x   = (const float*)d_in[0];
    const int*   ei  = (const int*)d_in[1];
    const float* W1  = (const float*)d_in[2];
    const float* b1  = (const float*)d_in[3];
    const float* W2  = (const float*)d_in[4];
    const float* b2  = (const float*)d_in[5];
    const float* fcw = (const float*)d_in[6];
    const float* fcb = (const float*)d_in[7];
    float* out = (float*)d_out;

    const long N = in_sizes[0] / 12;
    const long E = in_sizes[1] / 2;
    const int* src = ei;
    const int* dst = ei + E;

    char* ws = (char*)d_ws;
    size_t off = 0;
    auto alloc = [&](size_t bytes) {
        void* p = ws + off;
        off += (bytes + 255) & ~(size_t)255;
        return p;
    };
    // shared prefix (fallback path uses only these): 68MB
    unsigned* deg  = (unsigned*)alloc((size_t)N * 4);
    float*    dinv = (float*)alloc((size_t)N * 4);
    float*    y1   = (float*)alloc((size_t)N * 16 * 4);
    float*    acc1 = (float*)alloc((size_t)N * 16 * 4);
    float*    y2   = y1;            // y1 dead after layer-1 aggregation
    float*    acc2 = y1 + N * 8;
    // CSR extras
    const int NB = idiv_up(N, 1024);
    unsigned* row_start = (unsigned*)alloc((size_t)N * 4);
    unsigned* cursor    = (unsigned*)alloc((size_t)N * 4);
    int*      csr       = (int*)alloc((size_t)E * 4);
    unsigned* bsum      = (unsigned*)alloc((size_t)NB * 4);
    const bool use_csr = (off <= ws_size);  // constant per process -> capture-safe

    const int B = 256;
    const int EG = 2048;
    const int NG = idiv_up(N, B);

    hipMemsetAsync(deg, 0, (size_t)N * 4, stream);
    k_deg<<<EG, B, 0, stream>>>(dst, E, deg);
    k_dinv<<<NG, B, 0, stream>>>(deg, dinv, (int)N);

    if (use_csr) {
        k_bsum<<<NB, 256, 0, stream>>>(deg, (int)N, bsum);
        k_scan_boff<<<1, 512, 0, stream>>>(bsum, NB);
        k_scan_final<<<NB, 256, 0, stream>>>(deg, (int)N, bsum, row_start, cursor);
        k_scatter<<<EG, B, 0, stream>>>(src, dst, E, cursor, csr);
        // after k_scatter, cursor[d] == row_end[d]
        k_node1<<<NG, B, 0, stream>>>(x, W1, dinv, y1, acc1, (int)N);
        k_gather<16><<<idiv_up(N, 16), 256, 0, stream>>>(row_start, cursor, csr, y1, acc1, (int)N);
        k_node2<<<NG, B, 0, stream>>>(acc1, W2, b1, dinv, y2, acc2, (int)N);
        k_gather<8><<<idiv_up(N, 32), 256, 0, stream>>>(row_start, cursor, csr, y2, acc2, (int)N);
        k_node3<<<NG, B, 0, stream>>>(acc2, b2, fcw, fcb, dinv, out, (int)N);
    } else {
        k_node1<<<NG, B, 0, stream>>>(x, W1, dinv, y1, acc1, (int)N);
        k_edge<16><<<EG, B, 0, stream>>>(src, dst, E, y1, acc1);
        k_node2<<<NG, B, 0, stream>>>(acc1, W2, b1, dinv, y2, acc2, (int)N);
        k_edge<8><<<EG, B, 0, stream>>>(src, dst, E, y2, acc2);
        k_node3<<<NG, B, 0, stream>>>(acc2, b2, fcw, fcb, dinv, out, (int)N);
    }
}

// Round 3
// 1393.067 us; speedup vs baseline: 7.2217x; 1.0022x over previous
//
#include <hip/hip_runtime.h>
#include <math.h>

// GCN: h1 = relu(norm_agg(x@W1) + b1); h2 = relu(norm_agg(h1@W2) + b2);
// out = sigmoid(h2@fc_w + fc_b)
// norm_agg(z)[d] = dinv[d]*( sum_{s->d} dinv[s]*z[s] + dinv[d]*z[d] )
//
// Round 3: zero global atomics. Global atomics write ~32B through to HBM each
// (round-2 k_scatter: 502MB WRITE for 8M csr writes + 8M cursor atomics).
// New plan: dst-bucket partition (LDS histograms + matrix scan + LDS cursors),
// then per-bucket aggregation into LDS accumulators (ds_add_f32), coalesced out.

#define SHIFT 9
#define BSZ 512              // nodes per bucket (1<<SHIFT)
#define EB 2048              // edge-chunk blocks for hist/part
#define SRCMASK 0x7FFFFu     // 19 bits: N <= 524288

static inline int idiv_up(long a, long b) { return (int)((a + b - 1) / b); }

// ---------------- partition pass ----------------
// C[bucket*EB + block] = #edges in this block's chunk going to bucket
__global__ void k_hist(const int* __restrict__ dst, long E, long chunk,
                       unsigned* __restrict__ C, int NBUCK) {
    __shared__ unsigned cnt[1024];
    for (int t = threadIdx.x; t < 1024; t += 256) cnt[t] = 0u;
    __syncthreads();
    long e0 = (long)blockIdx.x * chunk;
    long e1 = e0 + chunk; if (e1 > E) e1 = E;
    for (long k = e0 + threadIdx.x; k < e1; k += 256)
        atomicAdd(&cnt[(unsigned)dst[k] >> SHIFT], 1u);
    __syncthreads();
    for (int bk = threadIdx.x; bk < NBUCK; bk += 256)
        C[(size_t)bk * EB + blockIdx.x] = cnt[bk];
}

// generic scan helpers (1024 elems per block)
__global__ void k_bsum(const unsigned* __restrict__ in, long L, unsigned* __restrict__ bsum) {
    __shared__ unsigned s[256];
    long base = (long)blockIdx.x * 1024 + threadIdx.x * 4;
    unsigned t = 0;
#pragma unroll
    for (int j = 0; j < 4; ++j) { long idx = base + j; if (idx < L) t += in[idx]; }
    s[threadIdx.x] = t;
    __syncthreads();
    for (int o = 128; o > 0; o >>= 1) {
        if (threadIdx.x < (unsigned)o) s[threadIdx.x] += s[threadIdx.x + o];
        __syncthreads();
    }
    if (threadIdx.x == 0) bsum[blockIdx.x] = s[0];
}

__global__ void k_scan_boff(unsigned* bsum, int NB) {
    __shared__ unsigned s[512];
    unsigned carry = 0;
    for (int base = 0; base < NB; base += 512) {
        int idx = base + threadIdx.x;
        unsigned v = (idx < NB) ? bsum[idx] : 0u;
        s[threadIdx.x] = v;
        __syncthreads();
        for (int o = 1; o < 512; o <<= 1) {
            unsigned a = (threadIdx.x >= (unsigned)o) ? s[threadIdx.x - o] : 0u;
            __syncthreads();
            s[threadIdx.x] += a;
            __syncthreads();
        }
        if (idx < NB) bsum[idx] = carry + s[threadIdx.x] - v;  // exclusive
        unsigned tot = s[511];
        __syncthreads();
        carry += tot;
    }
}

// exclusive scan, in-place safe (out may == in)
__global__ void k_scan_final(const unsigned* __restrict__ in, long L,
                             const unsigned* __restrict__ boff, unsigned* __restrict__ out) {
    __shared__ unsigned s[256];
    long base = (long)blockIdx.x * 1024 + threadIdx.x * 4;
    unsigned v[4]; unsigned t = 0;
#pragma unroll
    for (int j = 0; j < 4; ++j) { long idx = base + j; v[j] = (idx < L) ? in[idx] : 0u; t += v[j]; }
    s[threadIdx.x] = t;
    __syncthreads();
    for (int o = 1; o < 256; o <<= 1) {  // inclusive Hillis-Steele
        unsigned a = (threadIdx.x >= (unsigned)o) ? s[threadIdx.x - o] : 0u;
        __syncthreads();
        s[threadIdx.x] += a;
        __syncthreads();
    }
    unsigned run = s[threadIdx.x] - t + boff[blockIdx.x];  // exclusive + block offset
#pragma unroll
    for (int j = 0; j < 4; ++j) {
        long idx = base + j;
        if (idx < L) { out[idx] = run; run += v[j]; }
    }
}

// scatter edges into bucket-partitioned P using LDS cursors (no global atomics)
__global__ void k_part(const int* __restrict__ src, const int* __restrict__ dst, long E,
                       long chunk, const unsigned* __restrict__ Coff,
                       unsigned* __restrict__ P, int NBUCK) {
    __shared__ unsigned cur[1024];
    for (int bk = threadIdx.x; bk < NBUCK; bk += 256)
        cur[bk] = Coff[(size_t)bk * EB + blockIdx.x];
    __syncthreads();
    long e0 = (long)blockIdx.x * chunk;
    long e1 = e0 + chunk; if (e1 > E) e1 = E;
    for (long k = e0 + threadIdx.x; k < e1; k += 256) {
        unsigned s = (unsigned)src[k], d = (unsigned)dst[k];
        unsigned bk = d >> SHIFT;
        unsigned pos = atomicAdd(&cur[bk], 1u);  // LDS atomic
        P[pos] = s | ((d & (BSZ - 1u)) << 19);
    }
}

// per-bucket degree -> dinv (LDS histogram, no global atomics)
__global__ void k_bdeg(const unsigned* __restrict__ P, const unsigned* __restrict__ Coff,
                       long E, int NBUCK, float* __restrict__ dinv, int N) {
    __shared__ unsigned cnt[BSZ];
    for (int t = threadIdx.x; t < BSZ; t += 256) cnt[t] = 0u;
    int b = blockIdx.x;
    long bs = Coff[(size_t)b * EB];
    long be = (b + 1 < NBUCK) ? (long)Coff[(size_t)(b + 1) * EB] : E;
    __syncthreads();
    for (long k = bs + threadIdx.x; k < be; k += 256)
        atomicAdd(&cnt[P[k] >> 19], 1u);
    __syncthreads();
    int base = b << SHIFT;
    for (int t = threadIdx.x; t < BSZ; t += 256) {
        int node = base + t;
        if (node < N) dinv[node] = rsqrtf((float)(cnt[t] + 1u));  // +1 self-loop
    }
}

// ---------------- aggregation: acc[d] = sum_{s->d} y[s] + y[d] ----------------
template <int C>
__global__ void k_agg(const unsigned* __restrict__ P, const unsigned* __restrict__ Coff,
                      long E, int NBUCK, const float* __restrict__ y,
                      float* __restrict__ accG, int N) {
    __shared__ float sacc[C * BSZ];  // [channel][node-in-bucket]
    for (int t = threadIdx.x; t < C * BSZ; t += 256) sacc[t] = 0.f;
    int b = blockIdx.x;
    long bs = Coff[(size_t)b * EB];
    long be = (b + 1 < NBUCK) ? (long)Coff[(size_t)(b + 1) * EB] : E;
    __syncthreads();
    for (long k = bs + threadIdx.x; k < be; k += 256) {
        unsigned v = P[k];
        unsigned s = v & SRCMASK;
        unsigned dl = v >> 19;
        const float4* yp = (const float4*)(y + (size_t)s * C);
#pragma unroll
        for (int q = 0; q < C / 4; ++q) {
            float4 f = yp[q];
            atomicAdd(&sacc[(4 * q + 0) * BSZ + dl], f.x);  // ds_add_f32, bank=dl%32
            atomicAdd(&sacc[(4 * q + 1) * BSZ + dl], f.y);
            atomicAdd(&sacc[(4 * q + 2) * BSZ + dl], f.z);
            atomicAdd(&sacc[(4 * q + 3) * BSZ + dl], f.w);
        }
    }
    __syncthreads();
    int base = b << SHIFT;
    for (int t = threadIdx.x; t < BSZ; t += 256) {
        int node = base + t;
        if (node >= N) continue;
        const float* yn = y + (size_t)node * C;
        float4* op = (float4*)(accG + (size_t)node * C);
#pragma unroll
        for (int q = 0; q < C / 4; ++q) {
            float4 o;
            o.x = sacc[(4 * q + 0) * BSZ + t] + yn[4 * q + 0];  // + self-loop
            o.y = sacc[(4 * q + 1) * BSZ + t] + yn[4 * q + 1];
            o.z = sacc[(4 * q + 2) * BSZ + t] + yn[4 * q + 2];
            o.w = sacc[(4 * q + 3) * BSZ + t] + yn[4 * q + 3];
            op[q] = o;
        }
    }
}

// ---------------- fallback (round-1 style, global atomics) ----------------
__global__ void k_deg(const int* __restrict__ dst, long E, unsigned* __restrict__ deg) {
    long i = (long)blockIdx.x * blockDim.x + threadIdx.x;
    long stride = (long)gridDim.x * blockDim.x;
    for (long e = i; e < E; e += stride)
        atomicAdd(&deg[dst[e]], 1u);
}

__global__ void k_dinv(const unsigned* __restrict__ deg, float* __restrict__ dinv, int N) {
    int i = blockIdx.x * blockDim.x + threadIdx.x;
    if (i < N) dinv[i] = rsqrtf((float)(deg[i] + 1u));
}

template <int C>
__global__ void k_edge(const int* __restrict__ src, const int* __restrict__ dst, long E,
                       const float* __restrict__ y, float* __restrict__ acc) {
    long i = (long)blockIdx.x * blockDim.x + threadIdx.x;
    long stride = (long)gridDim.x * blockDim.x;
    for (long e = i; e < E; e += stride) {
        int s = src[e], d = dst[e];
        const float4* ys = (const float4*)(y + (size_t)s * C);
        float* ad = acc + (size_t)d * C;
#pragma unroll
        for (int q = 0; q < C / 4; ++q) {
            float4 v = ys[q];
            unsafeAtomicAdd(ad + 4 * q + 0, v.x);
            unsafeAtomicAdd(ad + 4 * q + 1, v.y);
            unsafeAtomicAdd(ad + 4 * q + 2, v.z);
            unsafeAtomicAdd(ad + 4 * q + 3, v.w);
        }
    }
}

// ---------------- node kernels (acc init pointer optional) ----------------
__global__ void k_node1(const float* __restrict__ x, const float* __restrict__ W1,
                        const float* __restrict__ dinv, float* __restrict__ y1,
                        float* __restrict__ acc1, int N) {
    __shared__ float sW[192];  // W1 [12][16]
    if (threadIdx.x < 192) sW[threadIdx.x] = W1[threadIdx.x];
    __syncthreads();
    int i = blockIdx.x * blockDim.x + threadIdx.x;
    if (i >= N) return;
    const float4* xp = (const float4*)(x + (size_t)i * 12);
    float4 a = xp[0], b = xp[1], c = xp[2];
    float xi[12] = {a.x, a.y, a.z, a.w, b.x, b.y, b.z, b.w, c.x, c.y, c.z, c.w};
    float di = dinv[i];
    float o[16];
#pragma unroll
    for (int cc = 0; cc < 16; ++cc) {
        float s = 0.f;
#pragma unroll
        for (int r = 0; r < 12; ++r) s = fmaf(xi[r], sW[r * 16 + cc], s);
        o[cc] = s * di;
    }
    float4* yp = (float4*)(y1 + (size_t)i * 16);
#pragma unroll
    for (int q = 0; q < 4; ++q) {
        float4 v = make_float4(o[4 * q], o[4 * q + 1], o[4 * q + 2], o[4 * q + 3]);
        yp[q] = v;
        if (acc1) ((float4*)(acc1 + (size_t)i * 16))[q] = v;
    }
}

__global__ void k_node2(const float* __restrict__ acc1, const float* __restrict__ W2,
                        const float* __restrict__ b1, const float* __restrict__ dinv,
                        float* __restrict__ y2, float* __restrict__ acc2, int N) {
    __shared__ float sW[128];  // W2 [16][8]
    __shared__ float sb[16];
    if (threadIdx.x < 128) sW[threadIdx.x] = W2[threadIdx.x];
    if (threadIdx.x < 16) sb[threadIdx.x] = b1[threadIdx.x];
    __syncthreads();
    int i = blockIdx.x * blockDim.x + threadIdx.x;
    if (i >= N) return;
    float di = dinv[i];
    const float4* ap = (const float4*)(acc1 + (size_t)i * 16);
    float h[16];
#pragma unroll
    for (int q = 0; q < 4; ++q) {
        float4 v = ap[q];
        h[4 * q + 0] = fmaxf(fmaf(v.x, di, sb[4 * q + 0]), 0.f);
        h[4 * q + 1] = fmaxf(fmaf(v.y, di, sb[4 * q + 1]), 0.f);
        h[4 * q + 2] = fmaxf(fmaf(v.z, di, sb[4 * q + 2]), 0.f);
        h[4 * q + 3] = fmaxf(fmaf(v.w, di, sb[4 * q + 3]), 0.f);
    }
    float o[8];
#pragma unroll
    for (int k = 0; k < 8; ++k) {
        float s = 0.f;
#pragma unroll
        for (int c = 0; c < 16; ++c) s = fmaf(h[c], sW[c * 8 + k], s);
        o[k] = s * di;
    }
    float4* yp = (float4*)(y2 + (size_t)i * 8);
#pragma unroll
    for (int q = 0; q < 2; ++q) {
        float4 v = make_float4(o[4 * q], o[4 * q + 1], o[4 * q + 2], o[4 * q + 3]);
        yp[q] = v;
        if (acc2) ((float4*)(acc2 + (size_t)i * 8))[q] = v;
    }
}

__global__ void k_node3(const float* __restrict__ acc2, const float* __restrict__ b2,
                        const float* __restrict__ fcw, const float* __restrict__ fcb,
                        const float* __restrict__ dinv, float* __restrict__ out, int N) {
    __shared__ float sb[8], sw[8], sfb[1];
    if (threadIdx.x < 8) {
        sb[threadIdx.x] = b2[threadIdx.x];
        sw[threadIdx.x] = fcw[threadIdx.x];
    }
    if (threadIdx.x == 0) sfb[0] = fcb[0];
    __syncthreads();
    int i = blockIdx.x * blockDim.x + threadIdx.x;
    if (i >= N) return;
    float di = dinv[i];
    const float4* ap = (const float4*)(acc2 + (size_t)i * 8);
    float s = sfb[0];
#pragma unroll
    for (int q = 0; q < 2; ++q) {
        float4 v = ap[q];
        s = fmaf(fmaxf(fmaf(v.x, di, sb[4 * q + 0]), 0.f), sw[4 * q + 0], s);
        s = fmaf(fmaxf(fmaf(v.y, di, sb[4 * q + 1]), 0.f), sw[4 * q + 1], s);
        s = fmaf(fmaxf(fmaf(v.z, di, sb[4 * q + 2]), 0.f), sw[4 * q + 2], s);
        s = fmaf(fmaxf(fmaf(v.w, di, sb[4 * q + 3]), 0.f), sw[4 * q + 3], s);
    }
    out[i] = 1.f / (1.f + expf(-s));
}

extern "C" void kernel_launch(void* const* d_in, const int* in_sizes, int n_in,
                              void* d_out, int out_size, void* d_ws, size_t ws_size,
                              hipStream_t stream) {
    const float* x   = (const float*)d_in[0];
    const int*   ei  = (const int*)d_in[1];
    const float* W1  = (const float*)d_in[2];
    const float* b1  = (const float*)d_in[3];
    const float* W2  = (const float*)d_in[4];
    const float* b2  = (const float*)d_in[5];
    const float* fcw = (const float*)d_in[6];
    const float* fcb = (const float*)d_in[7];
    float* out = (float*)d_out;

    const long N = in_sizes[0] / 12;
    const long E = in_sizes[1] / 2;
    const int* src = ei;
    const int* dst = ei + E;

    const int NBUCK = idiv_up(N, BSZ);
    const long L = (long)NBUCK * EB;     // C matrix entries
    const int NB2 = idiv_up(L, 1024);    // scan blocks
    const long chunk = (E + EB - 1) / EB;

    char* ws = (char*)d_ws;
    size_t off = 0;
    auto alloc = [&](size_t bytes) {
        void* p = ws + off;
        off += (bytes + 255) & ~(size_t)255;
        return p;
    };
    // new path layout
    unsigned* C    = (unsigned*)alloc((size_t)L * 4);      // in-place scanned -> Coff
    unsigned* bsum = (unsigned*)alloc((size_t)NB2 * 4);
    unsigned* P    = (unsigned*)alloc((size_t)E * 4);      // packed (src | dlow<<19)
    float*    dinv = (float*)alloc((size_t)N * 4);
    float*    y1   = (float*)alloc((size_t)N * 16 * 4);
    float*    acc1 = (float*)alloc((size_t)N * 16 * 4);
    float*    y2   = y1;            // y1 dead after agg1
    float*    acc2 = y1 + N * 8;
    const bool use_new = (N <= 524288) && (off <= ws_size);

    const int B = 256;
    const int NG = idiv_up(N, B);

    if (use_new) {
        k_hist<<<EB, B, 0, stream>>>(dst, E, chunk, C, NBUCK);
        k_bsum<<<NB2, B, 0, stream>>>(C, L, bsum);
        k_scan_boff<<<1, 512, 0, stream>>>(bsum, NB2);
        k_scan_final<<<NB2, B, 0, stream>>>(C, L, bsum, C);  // in-place -> Coff
        k_part<<<EB, B, 0, stream>>>(src, dst, E, chunk, C, P, NBUCK);
        k_bdeg<<<NBUCK, B, 0, stream>>>(P, C, E, NBUCK, dinv, (int)N);
        k_node1<<<NG, B, 0, stream>>>(x, W1, dinv, y1, nullptr, (int)N);
        k_agg<16><<<NBUCK, B, 0, stream>>>(P, C, E, NBUCK, y1, acc1, (int)N);
        k_node2<<<NG, B, 0, stream>>>(acc1, W2, b1, dinv, y2, nullptr, (int)N);
        k_agg<8><<<NBUCK, B, 0, stream>>>(P, C, E, NBUCK, y2, acc2, (int)N);
        k_node3<<<NG, B, 0, stream>>>(acc2, b2, fcw, fcb, dinv, out, (int)N);
    } else {
        // fallback: round-1 atomic path (68MB)
        size_t off2 = 0;
        auto alloc2 = [&](size_t bytes) {
            void* p = ws + off2;
            off2 += (bytes + 255) & ~(size_t)255;
            return p;
        };
        unsigned* degF  = (unsigned*)alloc2((size_t)N * 4);
        float*    dinvF = (float*)alloc2((size_t)N * 4);
        float*    y1F   = (float*)alloc2((size_t)N * 16 * 4);
        float*    acc1F = (float*)alloc2((size_t)N * 16 * 4);
        float*    y2F   = y1F;
        float*    acc2F = y1F + N * 8;
        const int EG = 2048;
        hipMemsetAsync(degF, 0, (size_t)N * 4, stream);
        k_deg<<<EG, B, 0, stream>>>(dst, E, degF);
        k_dinv<<<NG, B, 0, stream>>>(degF, dinvF, (int)N);
        k_node1<<<NG, B, 0, stream>>>(x, W1, dinvF, y1F, acc1F, (int)N);
        k_edge<16><<<EG, B, 0, stream>>>(src, dst, E, y1F, acc1F);
        k_node2<<<NG, B, 0, stream>>>(acc1F, W2, b1, dinvF, y2F, acc2F, (int)N);
        k_edge<8><<<EG, B, 0, stream>>>(src, dst, E, y2F, acc2F);
        k_node3<<<NG, B, 0, stream>>>(acc2F, b2, fcw, fcb, dinvF, out, (int)N);
    }
}